// Round 10
// baseline (48.708 us; speedup 1.0000x reference)
//
#include <hip/hip_runtime.h>
#include <hip/hip_fp16.h>

// Problem constants (reference: B,N,D,H,C = 4,512,128,128,3)
#define B_ 4
#define N_ 512
#define D_ 128
#define H_ 128
#define C_ 3

#define NEG_LOG2E   (-1.4426950408889634f)
#define NEG_HALF_LN2 (-0.34657359027997264f)   // -0.5 * ln(2)

typedef _Float16 half8  __attribute__((ext_vector_type(8)));
typedef _Float16 half4v __attribute__((ext_vector_type(4)));

__device__ __forceinline__ float exp2_fast(float x) {
    return __builtin_amdgcn_exp2f(x);   // raw v_exp_f32 (2^x)
}

// Projections stored PRE-SCALED by -log2e, in f16:
//   At[row][h] = f16(-log2e * (dot(h[row], W1[h][0:128]) + b1[h]))
//   Bt[row][h] = f16(-log2e *  dot(h[row], W1[h][128:256]))
__global__ __launch_bounds__(256) void proj_gemm(
    const float* __restrict__ hd, const float* __restrict__ W1,
    const float* __restrict__ b1, _Float16* __restrict__ At, _Float16* __restrict__ Bt)
{
    __shared__ float hsT[64][36];   // [k][m]
    __shared__ float wt [64][68];   // [k][o]
    const int m0      = blockIdx.x * 32;
    const int by      = blockIdx.y;        // 0..3
    const int halfSel = by >> 1;           // 0 -> At, 1 -> Bt
    const int wrow0   = (by & 1) * 64;     // W1 row base (== output h-col base)

    const int t  = threadIdx.x;
    const int r  = t >> 4, c4 = t & 15;
    const int tx = t & 15, ty = t >> 4;

    float acc[2][4] = {};

    for (int kc = 0; kc < 2; ++kc) {
        if (kc) __syncthreads();
        #pragma unroll
        for (int i = 0; i < 2; ++i) {
            const int m = r + 16 * i;
            float4 v = *(const float4*)&hd[(m0 + m) * D_ + kc * 64 + 4 * c4];
            hsT[4 * c4 + 0][m] = v.x; hsT[4 * c4 + 1][m] = v.y;
            hsT[4 * c4 + 2][m] = v.z; hsT[4 * c4 + 3][m] = v.w;
        }
        #pragma unroll
        for (int i = 0; i < 4; ++i) {
            const int o = r + 16 * i;
            float4 v = *(const float4*)&W1[(wrow0 + o) * (2 * D_) + halfSel * D_ + kc * 64 + 4 * c4];
            wt[4 * c4 + 0][o] = v.x; wt[4 * c4 + 1][o] = v.y;
            wt[4 * c4 + 2][o] = v.z; wt[4 * c4 + 3][o] = v.w;
        }
        __syncthreads();
        #pragma unroll 8
        for (int k = 0; k < 64; ++k) {
            float2 a  = *(const float2*)&hsT[k][2 * ty];
            float4 bv = *(const float4*)&wt [k][4 * tx];
            acc[0][0] = fmaf(a.x, bv.x, acc[0][0]); acc[0][1] = fmaf(a.x, bv.y, acc[0][1]);
            acc[0][2] = fmaf(a.x, bv.z, acc[0][2]); acc[0][3] = fmaf(a.x, bv.w, acc[0][3]);
            acc[1][0] = fmaf(a.y, bv.x, acc[1][0]); acc[1][1] = fmaf(a.y, bv.y, acc[1][1]);
            acc[1][2] = fmaf(a.y, bv.z, acc[1][2]); acc[1][3] = fmaf(a.y, bv.w, acc[1][3]);
        }
    }

    _Float16* dst = halfSel ? Bt : At;
    const int ocol = wrow0 + 4 * tx;
    float4 bias = make_float4(0.f, 0.f, 0.f, 0.f);
    if (!halfSel) bias = *(const float4*)&b1[ocol];
    #pragma unroll
    for (int i = 0; i < 2; ++i) {
        half4v o;
        o[0] = (_Float16)((acc[i][0] + bias.x) * NEG_LOG2E);
        o[1] = (_Float16)((acc[i][1] + bias.y) * NEG_LOG2E);
        o[2] = (_Float16)((acc[i][2] + bias.z) * NEG_LOG2E);
        o[3] = (_Float16)((acc[i][3] + bias.w) * NEG_LOG2E);
        *(half4v*)&dst[(m0 + 2 * ty + i) * H_ + ocol] = o;
    }
}

// One block per (batch, upper-tri 32x32 tile pair). 16x16 threads, each owns a
// 2x2 set of pairs: i in {ti, ti+16}, j in {tj, tj+16} -> 16 LDS reads per
// chunk serve 4 pairs (0.5 reads/pair-h instead of 1; LDS pipe was the
// bottleneck). Exp-factorized f16 math as round 9:
//   y1 = yA_i+yB_j, y2 = yA_j+yB_i; e1 = eA_i*eB_j, e2 = eA_j*eB_i (pk f16)
//   d = 1+e; s = f32(y1*d2+y2*d1) * rcp_f32(f32(d1*d2));  acc_c += s*W2[c][h]
// LDS: 8 tiles [32][64] f16 = 32 KB, chunk-XOR swizzle; h in 2 phases.
__global__ __launch_bounds__(256, 2) void pair_kernel(
    const _Float16* __restrict__ At, const _Float16* __restrict__ Bt,
    const float* __restrict__ W2, const float* __restrict__ b2,
    float* __restrict__ out)
{
    __shared__ _Float16 tiles[8][32 * 64];   // 0-3: yAI,yAJ,yBI,yBJ; 4-7: eAI,eAJ,eBI,eBJ
    const int T = N_ / 32;  // 16 tiles per dim
    int tp = blockIdx.x;
    const int b = blockIdx.y;
    int I = 0;
    while (tp >= T - I) { tp -= T - I; ++I; }   // uniform scalar decode
    const int J = I + tp;

    const int tid = threadIdx.x;
    // staging: wave w stages source tile w; lane l: row = l>>1, half = l&1
    const int stile = tid >> 6;            // wave-uniform: 0=AI,1=AJ,2=BI,3=BJ
    const int lane  = tid & 63;
    const int srow  = lane >> 1;           // 0..31
    const int shalf = lane & 1;            // chunk group 0..3 / 4..7
    const _Float16* gsrc = ((stile & 2) ? Bt : At)
        + (size_t)(b * N_ + ((stile & 1) ? J : I) * 32 + srow) * H_;
    _Float16* ybase = &tiles[stile][srow * 64];
    _Float16* ebase = &tiles[stile + 4][srow * 64];
    const int sxor = srow & 7;

    const int ti = tid >> 4, tj = tid & 15;
    const int xI = ti & 7, xJ = tj & 7;    // (ti+16)&7 == ti&7: shared by both rows

    float acc[4][3] = {};   // pairs: (0,0),(0,1),(1,0),(1,1) of (i-block, j-block)

    for (int ph = 0; ph < 2; ++ph) {
        if (ph) __syncthreads();   // all reads of previous phase done before overwrite
        #pragma unroll
        for (int q = 0; q < 4; ++q) {
            const int c = shalf * 4 + q;   // chunk 0..7 (8 f16 each)
            half8 yv = *(const half8*)&gsrc[ph * 64 + c * 8];
            half8 ev;
            #pragma unroll
            for (int e = 0; e < 8; ++e)
                ev[e] = (_Float16)exp2_fast((float)yv[e]);
            const int cs = (c ^ sxor) * 8;  // swizzled chunk slot
            *(half8*)&ybase[cs] = yv;
            *(half8*)&ebase[cs] = ev;
        }
        __syncthreads();

        for (int c = 0; c < 8; ++c) {
            const int oI0 =  ti       * 64 + ((c ^ xI) * 8);
            const int oI1 = (ti + 16) * 64 + ((c ^ xI) * 8);
            const int oJ0 =  tj       * 64 + ((c ^ xJ) * 8);
            const int oJ1 = (tj + 16) * 64 + ((c ^ xJ) * 8);
            half8 yAI0 = *(const half8*)&tiles[0][oI0], yAI1 = *(const half8*)&tiles[0][oI1];
            half8 yAJ0 = *(const half8*)&tiles[1][oJ0], yAJ1 = *(const half8*)&tiles[1][oJ1];
            half8 yBI0 = *(const half8*)&tiles[2][oI0], yBI1 = *(const half8*)&tiles[2][oI1];
            half8 yBJ0 = *(const half8*)&tiles[3][oJ0], yBJ1 = *(const half8*)&tiles[3][oJ1];
            half8 eAI0 = *(const half8*)&tiles[4][oI0], eAI1 = *(const half8*)&tiles[4][oI1];
            half8 eAJ0 = *(const half8*)&tiles[5][oJ0], eAJ1 = *(const half8*)&tiles[5][oJ1];
            half8 eBI0 = *(const half8*)&tiles[6][oI0], eBI1 = *(const half8*)&tiles[6][oI1];
            half8 eBJ0 = *(const half8*)&tiles[7][oJ0], eBJ1 = *(const half8*)&tiles[7][oJ1];

            const int hb = ph * 64 + c * 8;
            float4 w0a = *(const float4*)&W2[hb],          w0b = *(const float4*)&W2[hb + 4];
            float4 w1a = *(const float4*)&W2[H_ + hb],     w1b = *(const float4*)&W2[H_ + hb + 4];
            float4 w2a = *(const float4*)&W2[2 * H_ + hb], w2b = *(const float4*)&W2[2 * H_ + hb + 4];
            const float w0[8] = {w0a.x, w0a.y, w0a.z, w0a.w, w0b.x, w0b.y, w0b.z, w0b.w};
            const float w1[8] = {w1a.x, w1a.y, w1a.z, w1a.w, w1b.x, w1b.y, w1b.z, w1b.w};
            const float w2[8] = {w2a.x, w2a.y, w2a.z, w2a.w, w2b.x, w2b.y, w2b.z, w2b.w};

            #define SILU4(p, yAIv, yBIv, eAIv, eBIv, yAJv, yBJv, eAJv, eBJv)      \
            {                                                                     \
                half8 y1 = (yAIv) + (yBJv);                                       \
                half8 y2 = (yAJv) + (yBIv);                                       \
                half8 e1 = (eAIv) * (eBJv);                                       \
                half8 e2 = (eAJv) * (eBIv);                                       \
                half8 d1 = e1 + (_Float16)1.0f;                                   \
                half8 d2 = e2 + (_Float16)1.0f;                                   \
                half8 pp = d1 * d2;                                               \
                half8 num = y1 * d2 + y2 * d1;                                    \
                _Pragma("unroll")                                                 \
                for (int e = 0; e < 8; ++e) {                                     \
                    const float s = (float)num[e]                                 \
                                  * __builtin_amdgcn_rcpf((float)pp[e]);          \
                    acc[p][0] = fmaf(s, w0[e], acc[p][0]);                        \
                    acc[p][1] = fmaf(s, w1[e], acc[p][1]);                        \
                    acc[p][2] = fmaf(s, w2[e], acc[p][2]);                        \
                }                                                                 \
            }
            SILU4(0, yAI0, yBI0, eAI0, eBI0, yAJ0, yBJ0, eAJ0, eBJ0)
            SILU4(1, yAI0, yBI0, eAI0, eBI0, yAJ1, yBJ1, eAJ1, eBJ1)
            SILU4(2, yAI1, yBI1, eAI1, eBI1, yAJ0, yBJ0, eAJ0, eBJ0)
            SILU4(3, yAI1, yBI1, eAI1, eBI1, yAJ1, yBJ1, eAJ1, eBJ1)
            #undef SILU4
        }
    }

    const float b20 = b2[0], b21 = b2[1], b22 = b2[2];
    #pragma unroll
    for (int p = 0; p < 4; ++p) {
        const int i = I * 32 + ti + (p >> 1) * 16;
        const int j = J * 32 + tj + (p & 1) * 16;
        const float o0 = fmaf(NEG_HALF_LN2, acc[p][0], b20);
        const float o1 = fmaf(NEG_HALF_LN2, acc[p][1], b21);
        const float o2 = fmaf(NEG_HALF_LN2, acc[p][2], b22);
        float* p1 = out + ((size_t)(b * N_ + i) * N_ + j) * C_;
        float* p2 = out + ((size_t)(b * N_ + j) * N_ + i) * C_;
        p1[0] = o0; p1[1] = o1; p1[2] = o2;
        p2[0] = o0; p2[1] = o1; p2[2] = o2;   // diagonal tiles: identical duplicate, benign
    }
}

extern "C" void kernel_launch(void* const* d_in, const int* in_sizes, int n_in,
                              void* d_out, int out_size, void* d_ws, size_t ws_size,
                              hipStream_t stream) {
    const float* hd = (const float*)d_in[0];
    const float* W1 = (const float*)d_in[1];
    const float* b1 = (const float*)d_in[2];
    const float* W2 = (const float*)d_in[3];
    const float* b2 = (const float*)d_in[4];
    float* out = (float*)d_out;

    _Float16* At = (_Float16*)d_ws;          // [B*N][H] f16 = 512 KiB (scaled by -log2e)
    _Float16* Bt = At + B_ * N_ * H_;        // [B*N][H] f16 = 512 KiB

    proj_gemm<<<dim3((B_ * N_) / 32, 4), dim3(256), 0, stream>>>(hd, W1, b1, At, Bt);

    const int T = N_ / 32;                   // 16 -> 136 upper-tri tile pairs
    pair_kernel<<<dim3(T * (T + 1) / 2, B_), dim3(256), 0, stream>>>(At, Bt, W2, b2, out);
}

// Round 11
// 47.998 us; speedup vs baseline: 1.0148x; 1.0148x over previous
//
#include <hip/hip_runtime.h>
#include <hip/hip_fp16.h>

// Problem constants (reference: B,N,D,H,C = 4,512,128,128,3)
#define B_ 4
#define N_ 512
#define D_ 128
#define H_ 128
#define C_ 3

#define NEG_LOG2E   (-1.4426950408889634f)
#define NEG_HALF_LN2 (-0.34657359027997264f)   // -0.5 * ln(2)

#define PH   4     // h phases in pair kernel
#define PHH  32    // h per phase
#define TROW 40    // padded f16 row stride: 80 B = 20 banks, gcd(20,32)=4 -> <=2-way reads

typedef _Float16 half8  __attribute__((ext_vector_type(8)));
typedef _Float16 half4v __attribute__((ext_vector_type(4)));

__device__ __forceinline__ float exp2_fast(float x) {
    return __builtin_amdgcn_exp2f(x);   // raw v_exp_f32 (2^x)
}

// Projections stored PRE-SCALED by -log2e, in f16:
//   At[row][h] = f16(-log2e * (dot(h[row], W1[h][0:128]) + b1[h]))
//   Bt[row][h] = f16(-log2e *  dot(h[row], W1[h][128:256]))
__global__ __launch_bounds__(256) void proj_gemm(
    const float* __restrict__ hd, const float* __restrict__ W1,
    const float* __restrict__ b1, _Float16* __restrict__ At, _Float16* __restrict__ Bt)
{
    __shared__ float hsT[64][36];   // [k][m]
    __shared__ float wt [64][68];   // [k][o]
    const int m0      = blockIdx.x * 32;
    const int by      = blockIdx.y;        // 0..3
    const int halfSel = by >> 1;           // 0 -> At, 1 -> Bt
    const int wrow0   = (by & 1) * 64;     // W1 row base (== output h-col base)

    const int t  = threadIdx.x;
    const int r  = t >> 4, c4 = t & 15;
    const int tx = t & 15, ty = t >> 4;

    float acc[2][4] = {};

    for (int kc = 0; kc < 2; ++kc) {
        if (kc) __syncthreads();
        #pragma unroll
        for (int i = 0; i < 2; ++i) {
            const int m = r + 16 * i;
            float4 v = *(const float4*)&hd[(m0 + m) * D_ + kc * 64 + 4 * c4];
            hsT[4 * c4 + 0][m] = v.x; hsT[4 * c4 + 1][m] = v.y;
            hsT[4 * c4 + 2][m] = v.z; hsT[4 * c4 + 3][m] = v.w;
        }
        #pragma unroll
        for (int i = 0; i < 4; ++i) {
            const int o = r + 16 * i;
            float4 v = *(const float4*)&W1[(wrow0 + o) * (2 * D_) + halfSel * D_ + kc * 64 + 4 * c4];
            wt[4 * c4 + 0][o] = v.x; wt[4 * c4 + 1][o] = v.y;
            wt[4 * c4 + 2][o] = v.z; wt[4 * c4 + 3][o] = v.w;
        }
        __syncthreads();
        #pragma unroll 8
        for (int k = 0; k < 64; ++k) {
            float2 a  = *(const float2*)&hsT[k][2 * ty];
            float4 bv = *(const float4*)&wt [k][4 * tx];
            acc[0][0] = fmaf(a.x, bv.x, acc[0][0]); acc[0][1] = fmaf(a.x, bv.y, acc[0][1]);
            acc[0][2] = fmaf(a.x, bv.z, acc[0][2]); acc[0][3] = fmaf(a.x, bv.w, acc[0][3]);
            acc[1][0] = fmaf(a.y, bv.x, acc[1][0]); acc[1][1] = fmaf(a.y, bv.y, acc[1][1]);
            acc[1][2] = fmaf(a.y, bv.z, acc[1][2]); acc[1][3] = fmaf(a.y, bv.w, acc[1][3]);
        }
    }

    _Float16* dst = halfSel ? Bt : At;
    const int ocol = wrow0 + 4 * tx;
    float4 bias = make_float4(0.f, 0.f, 0.f, 0.f);
    if (!halfSel) bias = *(const float4*)&b1[ocol];
    #pragma unroll
    for (int i = 0; i < 2; ++i) {
        half4v o;
        o[0] = (_Float16)((acc[i][0] + bias.x) * NEG_LOG2E);
        o[1] = (_Float16)((acc[i][1] + bias.y) * NEG_LOG2E);
        o[2] = (_Float16)((acc[i][2] + bias.z) * NEG_LOG2E);
        o[3] = (_Float16)((acc[i][3] + bias.w) * NEG_LOG2E);
        *(half4v*)&dst[(m0 + 2 * ty + i) * H_ + ocol] = o;
    }
}

// One block per (batch, upper-tri 32x32 tile pair). 16x16 threads, each owns a
// 2x2 set of pairs: i in {ti, ti+16}, j in {tj, tj+16} -> 16 LDS reads per
// 8-h chunk serve 4 pairs. Exp-factorized f16 math (e^(yi+yj) = Ei*Ej, exps
// once per row at staging). h split into 4 phases of 32 so the 8 tiles are
// [32][40] f16 = 20480 B total -> 3 blocks/CU resident (round 10's 32 KB
// left only 1 resident block and latency-stalled). Pad-40 row stride makes
// all compute reads <=2-way (free); no swizzle.
__global__ __launch_bounds__(256, 3) void pair_kernel(
    const _Float16* __restrict__ At, const _Float16* __restrict__ Bt,
    const float* __restrict__ W2, const float* __restrict__ b2,
    float* __restrict__ out)
{
    __shared__ __align__(16) _Float16 tiles[8][32 * TROW];  // 0-3: yAI,yAJ,yBI,yBJ; 4-7: e*
    const int T = N_ / 32;  // 16 tiles per dim
    int tp = blockIdx.x;
    const int b = blockIdx.y;
    int I = 0;
    while (tp >= T - I) { tp -= T - I; ++I; }   // uniform scalar decode
    const int J = I + tp;

    const int tid = threadIdx.x;
    // staging: wave w stages source tile w; lane l: row = l>>1, chunk pair = l&1
    const int stile = tid >> 6;            // wave-uniform: 0=AI,1=AJ,2=BI,3=BJ
    const int lane  = tid & 63;
    const int srow  = lane >> 1;           // 0..31
    const int scp   = lane & 1;            // chunks {0,1} or {2,3}
    const _Float16* gsrc = ((stile & 2) ? Bt : At)
        + (size_t)(b * N_ + ((stile & 1) ? J : I) * 32 + srow) * H_;
    _Float16* ybase = &tiles[stile][srow * TROW];
    _Float16* ebase = &tiles[stile + 4][srow * TROW];

    const int ti = tid >> 4, tj = tid & 15;
    float acc[4][3] = {};   // pairs: (i-blk, j-blk) = (0,0),(0,1),(1,0),(1,1)

    for (int ph = 0; ph < PH; ++ph) {
        if (ph) __syncthreads();   // reads of previous phase done before overwrite
        #pragma unroll
        for (int q = 0; q < 2; ++q) {
            const int c = scp * 2 + q;     // chunk 0..3 (8 f16 each)
            half8 yv = *(const half8*)&gsrc[ph * PHH + c * 8];
            half8 ev;
            #pragma unroll
            for (int e = 0; e < 8; ++e)
                ev[e] = (_Float16)exp2_fast((float)yv[e]);
            *(half8*)&ybase[c * 8] = yv;
            *(half8*)&ebase[c * 8] = ev;
        }
        __syncthreads();

        #pragma unroll 2
        for (int c = 0; c < 4; ++c) {
            const int oI0 =  ti       * TROW + c * 8;
            const int oI1 = (ti + 16) * TROW + c * 8;
            const int oJ0 =  tj       * TROW + c * 8;
            const int oJ1 = (tj + 16) * TROW + c * 8;
            half8 yAI0 = *(const half8*)&tiles[0][oI0], yAI1 = *(const half8*)&tiles[0][oI1];
            half8 yAJ0 = *(const half8*)&tiles[1][oJ0], yAJ1 = *(const half8*)&tiles[1][oJ1];
            half8 yBI0 = *(const half8*)&tiles[2][oI0], yBI1 = *(const half8*)&tiles[2][oI1];
            half8 yBJ0 = *(const half8*)&tiles[3][oJ0], yBJ1 = *(const half8*)&tiles[3][oJ1];
            half8 eAI0 = *(const half8*)&tiles[4][oI0], eAI1 = *(const half8*)&tiles[4][oI1];
            half8 eAJ0 = *(const half8*)&tiles[5][oJ0], eAJ1 = *(const half8*)&tiles[5][oJ1];
            half8 eBI0 = *(const half8*)&tiles[6][oI0], eBI1 = *(const half8*)&tiles[6][oI1];
            half8 eBJ0 = *(const half8*)&tiles[7][oJ0], eBJ1 = *(const half8*)&tiles[7][oJ1];

            const int hb = ph * PHH + c * 8;
            float4 w0a = *(const float4*)&W2[hb],          w0b = *(const float4*)&W2[hb + 4];
            float4 w1a = *(const float4*)&W2[H_ + hb],     w1b = *(const float4*)&W2[H_ + hb + 4];
            float4 w2a = *(const float4*)&W2[2 * H_ + hb], w2b = *(const float4*)&W2[2 * H_ + hb + 4];
            const float w0[8] = {w0a.x, w0a.y, w0a.z, w0a.w, w0b.x, w0b.y, w0b.z, w0b.w};
            const float w1[8] = {w1a.x, w1a.y, w1a.z, w1a.w, w1b.x, w1b.y, w1b.z, w1b.w};
            const float w2[8] = {w2a.x, w2a.y, w2a.z, w2a.w, w2b.x, w2b.y, w2b.z, w2b.w};

            #define SILU4(p, yAIv, yBIv, eAIv, eBIv, yAJv, yBJv, eAJv, eBJv)      \
            {                                                                     \
                half8 y1 = (yAIv) + (yBJv);                                       \
                half8 y2 = (yAJv) + (yBIv);                                       \
                half8 e1 = (eAIv) * (eBJv);                                       \
                half8 e2 = (eAJv) * (eBIv);                                       \
                half8 d1 = e1 + (_Float16)1.0f;                                   \
                half8 d2 = e2 + (_Float16)1.0f;                                   \
                half8 pp = d1 * d2;                                               \
                half8 num = y1 * d2 + y2 * d1;                                    \
                _Pragma("unroll")                                                 \
                for (int e = 0; e < 8; ++e) {                                     \
                    const float s = (float)num[e]                                 \
                                  * __builtin_amdgcn_rcpf((float)pp[e]);          \
                    acc[p][0] = fmaf(s, w0[e], acc[p][0]);                        \
                    acc[p][1] = fmaf(s, w1[e], acc[p][1]);                        \
                    acc[p][2] = fmaf(s, w2[e], acc[p][2]);                        \
                }                                                                 \
            }
            SILU4(0, yAI0, yBI0, eAI0, eBI0, yAJ0, yBJ0, eAJ0, eBJ0)
            SILU4(1, yAI0, yBI0, eAI0, eBI0, yAJ1, yBJ1, eAJ1, eBJ1)
            SILU4(2, yAI1, yBI1, eAI1, eBI1, yAJ0, yBJ0, eAJ0, eBJ0)
            SILU4(3, yAI1, yBI1, eAI1, eBI1, yAJ1, yBJ1, eAJ1, eBJ1)
            #undef SILU4
        }
    }

    const float b20 = b2[0], b21 = b2[1], b22 = b2[2];
    #pragma unroll
    for (int p = 0; p < 4; ++p) {
        const int i = I * 32 + ti + (p >> 1) * 16;
        const int j = J * 32 + tj + (p & 1) * 16;
        const float o0 = fmaf(NEG_HALF_LN2, acc[p][0], b20);
        const float o1 = fmaf(NEG_HALF_LN2, acc[p][1], b21);
        const float o2 = fmaf(NEG_HALF_LN2, acc[p][2], b22);
        float* p1 = out + ((size_t)(b * N_ + i) * N_ + j) * C_;
        float* p2 = out + ((size_t)(b * N_ + j) * N_ + i) * C_;
        p1[0] = o0; p1[1] = o1; p1[2] = o2;
        p2[0] = o0; p2[1] = o1; p2[2] = o2;   // diagonal tiles: identical duplicate, benign
    }
}

extern "C" void kernel_launch(void* const* d_in, const int* in_sizes, int n_in,
                              void* d_out, int out_size, void* d_ws, size_t ws_size,
                              hipStream_t stream) {
    const float* hd = (const float*)d_in[0];
    const float* W1 = (const float*)d_in[1];
    const float* b1 = (const float*)d_in[2];
    const float* W2 = (const float*)d_in[3];
    const float* b2 = (const float*)d_in[4];
    float* out = (float*)d_out;

    _Float16* At = (_Float16*)d_ws;          // [B*N][H] f16 = 512 KiB (scaled by -log2e)
    _Float16* Bt = At + B_ * N_ * H_;        // [B*N][H] f16 = 512 KiB

    proj_gemm<<<dim3((B_ * N_) / 32, 4), dim3(256), 0, stream>>>(hd, W1, b1, At, Bt);

    const int T = N_ / 32;                   // 16 -> 136 upper-tri tile pairs
    pair_kernel<<<dim3(T * (T + 1) / 2, B_), dim3(256), 0, stream>>>(At, Bt, W2, b2, out);
}